// Round 7
// baseline (149.054 us; speedup 1.0000x reference)
//
#include <hip/hip_runtime.h>

// RecursiveNN: 11-level binary tree, shared linear map W(128x256)+b, bf16 MFMA.
// pack_w: W -> per-lane MFMA B-fragment order (bf16).
// tree128: one block = 128 contiguous leaves; fp32 gather + packed cvt into a
//   144-row XOR-swizzled LDS arena (36,864 B -> 3 blocks/CU). In-place level
//   schedule with disjoint read/write row sets: 8 MFMA tiles, 6 barriers,
//   levels 128->8; the 8 roots go straight from D-regs to global (bf16).
//   4-way N-split (wave owns 32 cols, wf[16] = 64 VGPR) — the 2x2 split (R6)
//   regressed: latency/occupancy-bound, not LDS-BW-bound.
// finish: one block = one batch; 128 rows -> 1; fp32 output.

typedef __bf16 bf16x8 __attribute__((ext_vector_type(8)));
typedef __bf16 bf16x4 __attribute__((ext_vector_type(4)));
typedef float f32x4 __attribute__((ext_vector_type(4)));

#define NROWS 144  // 128-row working set + 16 spare; 144*256B = 36,864 B

// Swizzled LDS offset: row stride 128 elems (256 B); 16B chunk ^ (row & 15).
// Conflict-free for all access patterns here (0 conflicts measured R5/R6).
// Producer and consumer always use the same PHYSICAL row -> always consistent.
__device__ __forceinline__ int sw_off(int row, int col) {
    return row * 128 + ((((col >> 3) ^ (row & 15)) << 3) | (col & 7));
}

// Pack W (fp32 128x256) into MFMA B-fragment lane order (bf16):
//   frag gf = nt*8 + kk (N-tile nt = output cols nt*16..+15), lane l:
//   elem j = W[o][d+j], o = nt*16 + (l&15), d = kk*32 + (l>>4)*8.
__global__ void pack_w_kernel(const float* __restrict__ W,
                              __bf16* __restrict__ wpack) {
    const int gf = blockIdx.x;       // 0..63
    const int l = threadIdx.x;       // 0..63
    const int nt = gf >> 3, kk = gf & 7;
    const int o = nt * 16 + (l & 15);
    const int d = kk * 32 + ((l >> 4) << 3);
    const float* src = W + o * 256 + d;
    bf16x8 h;
#pragma unroll
    for (int j = 0; j < 8; ++j) h[j] = (__bf16)src[j];
    *(bf16x8*)(wpack + (size_t)(gf * 64 + l) * 8) = h;
}

// One 16-row M-tile, 4-way N-split (this wave's 32 cols). Input node j
// (j = 2*me + k-half) maps to physical row: MODE 0: off+j;
// MODE 1: j<16 ? 128+j : j-16 (the post-L1 piecewise layout).
// Writes NOUT rows at physical rows dstb..dstb+NOUT-1. No barrier inside.
template <int NOUT, int MODE>
__device__ __forceinline__ void step(
    __bf16* __restrict__ L, int off, int dstb,
    const bf16x8* wf, const float* bval, int wv, int q, int lm)
{
    const int me = (NOUT >= 16) ? lm : (lm < NOUT ? lm : 0);  // clamp->bcast
    f32x4 acc[2];
    acc[0] = (f32x4){ bval[0], bval[0], bval[0], bval[0] };
    acc[1] = (f32x4){ bval[1], bval[1], bval[1], bval[1] };
#pragma unroll
    for (int kk = 0; kk < 8; ++kk) {
        const int j = 2 * me + (kk >> 2);
        const int row = MODE ? (j < 16 ? 128 + j : j - 16) : off + j;
        const int col = (kk & 3) * 32 + q * 8;
        const bf16x8 af = *(const bf16x8*)&L[sw_off(row, col)];
        acc[0] = __builtin_amdgcn_mfma_f32_16x16x32_bf16(af, wf[kk],     acc[0], 0, 0, 0);
        acc[1] = __builtin_amdgcn_mfma_f32_16x16x32_bf16(af, wf[8 + kk], acc[1], 0, 0, 0);
    }
#pragma unroll
    for (int nl = 0; nl < 2; ++nl) {
        const int col = (2 * wv + nl) * 16 + lm;       // D col = lane&15
        const bf16x4 hv = __builtin_convertvector(acc[nl], bf16x4);
#pragma unroll
        for (int r = 0; r < 4; ++r) {
            const int row = q * 4 + r;                 // D row = quad*4+reg
            if (NOUT >= 16 || row < NOUT)
                L[sw_off(dstb + row, col)] = hv[r];
        }
    }
}

// 16 -> 8 with the 8 outputs written straight to global (bf16 rows of yrow).
__device__ __forceinline__ void step8_to_global(
    const __bf16* __restrict__ L, int off, __bf16* __restrict__ yrow,
    const bf16x8* wf, const float* bval, int wv, int q, int lm)
{
    const int me = (lm < 8) ? lm : 0;
    f32x4 acc[2];
    acc[0] = (f32x4){ bval[0], bval[0], bval[0], bval[0] };
    acc[1] = (f32x4){ bval[1], bval[1], bval[1], bval[1] };
#pragma unroll
    for (int kk = 0; kk < 8; ++kk) {
        const int j = 2 * me + (kk >> 2);
        const int col = (kk & 3) * 32 + q * 8;
        const bf16x8 af = *(const bf16x8*)&L[sw_off(off + j, col)];
        acc[0] = __builtin_amdgcn_mfma_f32_16x16x32_bf16(af, wf[kk],     acc[0], 0, 0, 0);
        acc[1] = __builtin_amdgcn_mfma_f32_16x16x32_bf16(af, wf[8 + kk], acc[1], 0, 0, 0);
    }
#pragma unroll
    for (int nl = 0; nl < 2; ++nl) {
        const int col = (2 * wv + nl) * 16 + lm;
#pragma unroll
        for (int r = 0; r < 4; ++r) {
            const int row = q * 4 + r;
            if (row < 8)
                yrow[(size_t)row * 128 + col] = (__bf16)acc[nl][r];
        }
    }
}

// Kernel 1: one block = 128 contiguous leaves of one batch; levels 128->8.
// Row schedule (disjoint read/write sets per barrier interval):
//   gather -> rows 0..127                                  | barrier
//   L1 T0: rows  0-31  -> 128-143                          | barrier
//   L1 T1: rows 32-63  -> 0-15                             | barrier
//   L1 T2: rows 64-95  -> 16-31   (disjoint with T3)
//   L1 T3: rows 96-127 -> 32-47                            | barrier
//   node n(0..63) now at row: n<16 ? 128+n : n-16  (MODE 1)
//   L2 T0: nodes  0-31 -> rows 48-63   (piecewise reads)
//   L2 T1: nodes 32-63 (rows 16-47) -> rows 64-79          | barrier
//   L3:    rows 48-79 -> rows 0-15                         | barrier
//   L4:    rows 0-15  -> 8 rows straight to global y
__global__ __launch_bounds__(256) void tree128_kernel(
    const int* __restrict__ wid, const float* __restrict__ emb,
    const __bf16* __restrict__ wpack, const float* __restrict__ bias,
    __bf16* __restrict__ yout)
{
    __shared__ __align__(16) __bf16 L[NROWS * 128];  // 36,864 B
    const int tid = threadIdx.x;
    const int batch = blockIdx.x >> 4;   // 16 groups of 128 leaves per batch
    const int grp = blockIdx.x & 15;
    const int wv = tid >> 6, ln = tid & 63, q = ln >> 4, lm = ln & 15;

    // Gather 128 rows x 128 fp32 -> bf16 swizzled LDS (512B coalesced runs).
    {
        const int* wb = wid + batch * 2048 + grp * 128;
        int idreg[16];
#pragma unroll
        for (int i = 0; i < 16; ++i) idreg[i] = wb[(tid >> 5) + 8 * i];
#pragma unroll
        for (int i = 0; i < 16; ++i) {
            const int row = (tid >> 5) + 8 * i;
            const int c4 = tid & 31;
            const f32x4 v =
                *(const f32x4*)(emb + (size_t)idreg[i] * 128 + c4 * 4);
            *(bf16x4*)&L[sw_off(row, c4 * 4)] =
                __builtin_convertvector(v, bf16x4);
        }
    }

    // W fragments for this wave's 32 cols (N-tiles 2wv, 2wv+1): 64 VGPRs.
    bf16x8 wf[16];
    const bf16x8* wp = (const bf16x8*)wpack;
#pragma unroll
    for (int f = 0; f < 16; ++f) wf[f] = wp[(16 * wv + f) * 64 + ln];
    float bval[2];
    bval[0] = bias[(2 * wv + 0) * 16 + lm];
    bval[1] = bias[(2 * wv + 1) * 16 + lm];

    __syncthreads();
    step<16, 0>(L, 0, 128, wf, bval, wv, q, lm);   // L1 T0
    __syncthreads();
    step<16, 0>(L, 32, 0, wf, bval, wv, q, lm);    // L1 T1
    __syncthreads();
    step<16, 0>(L, 64, 16, wf, bval, wv, q, lm);   // L1 T2
    step<16, 0>(L, 96, 32, wf, bval, wv, q, lm);   // L1 T3
    __syncthreads();
    step<16, 1>(L, 0, 48, wf, bval, wv, q, lm);    // L2 T0 (piecewise)
    step<16, 0>(L, 16, 64, wf, bval, wv, q, lm);   // L2 T1
    __syncthreads();
    step<16, 0>(L, 48, 0, wf, bval, wv, q, lm);    // L3
    __syncthreads();
    step8_to_global(L, 0, yout + (size_t)(batch * 128 + grp * 8) * 128,
                    wf, bval, wv, q, lm);           // L4 -> 8 global rows
}

// Kernel 2: one block = one batch; 128 subtree roots -> 1 row (fp32).
__global__ __launch_bounds__(256) void finish_kernel(
    const __bf16* __restrict__ yin, const __bf16* __restrict__ wpack,
    const float* __restrict__ bias, float* __restrict__ out)
{
    __shared__ __align__(16) __bf16 L[NROWS * 128];  // 36,864 B
    const int tid = threadIdx.x;
    const int batch = blockIdx.x;
    const int wv = tid >> 6, ln = tid & 63, q = ln >> 4, lm = ln & 15;

    bf16x8 wf[16];
    const bf16x8* wp = (const bf16x8*)wpack;
#pragma unroll
    for (int f = 0; f < 16; ++f) wf[f] = wp[(16 * wv + f) * 64 + ln];
    float bval[2];
    bval[0] = bias[(2 * wv + 0) * 16 + lm];
    bval[1] = bias[(2 * wv + 1) * 16 + lm];

    // Load 128 rows x 128 bf16 (2048 x 16B chunks, 8 per thread, coalesced).
#pragma unroll
    for (int i = 0; i < 8; ++i) {
        const int flat = tid + 256 * i;
        const int row = flat >> 4;
        const int c8 = flat & 15;
        const bf16x8 v =
            *(const bf16x8*)(yin + (size_t)(batch * 128 + row) * 128 + c8 * 8);
        *(bf16x8*)&L[sw_off(row, c8 * 8)] = v;
    }
    __syncthreads();

    step<16, 0>(L, 0, 128, wf, bval, wv, q, lm);   // 128->64 T0
    __syncthreads();
    step<16, 0>(L, 32, 0, wf, bval, wv, q, lm);    // T1
    __syncthreads();
    step<16, 0>(L, 64, 16, wf, bval, wv, q, lm);   // T2
    step<16, 0>(L, 96, 32, wf, bval, wv, q, lm);   // T3
    __syncthreads();
    step<16, 1>(L, 0, 48, wf, bval, wv, q, lm);    // 64->32 T0 (piecewise)
    step<16, 0>(L, 16, 64, wf, bval, wv, q, lm);   // 64->32 T1
    __syncthreads();
    step<16, 0>(L, 48, 0, wf, bval, wv, q, lm);    // 32->16: rows 48-79 -> 0-15
    __syncthreads();
    step<8, 0>(L, 0, 16, wf, bval, wv, q, lm);     // 16->8: rows 0-15 -> 16-23
    __syncthreads();
    step<4, 0>(L, 16, 0, wf, bval, wv, q, lm);     // 8->4: rows 16-23 -> 0-3
    __syncthreads();
    step<2, 0>(L, 0, 8, wf, bval, wv, q, lm);      // 4->2: rows 0-3 -> 8-9
    __syncthreads();

    // 2 -> 1: input rows 8,9; D row 0 = quad 0 reg 0; fp32 output.
    {
        f32x4 acc[2];
        acc[0] = (f32x4){ bval[0], bval[0], bval[0], bval[0] };
        acc[1] = (f32x4){ bval[1], bval[1], bval[1], bval[1] };
#pragma unroll
        for (int kk = 0; kk < 8; ++kk) {
            const int row = 8 + (kk >> 2);
            const int col = (kk & 3) * 32 + q * 8;
            const bf16x8 af = *(const bf16x8*)&L[sw_off(row, col)];
            acc[0] = __builtin_amdgcn_mfma_f32_16x16x32_bf16(af, wf[kk],     acc[0], 0, 0, 0);
            acc[1] = __builtin_amdgcn_mfma_f32_16x16x32_bf16(af, wf[8 + kk], acc[1], 0, 0, 0);
        }
        if (q == 0) {
#pragma unroll
            for (int nl = 0; nl < 2; ++nl)
                out[(size_t)batch * 128 + (2 * wv + nl) * 16 + lm] = acc[nl][0];
        }
    }
}

extern "C" void kernel_launch(void* const* d_in, const int* in_sizes, int n_in,
                              void* d_out, int out_size, void* d_ws, size_t ws_size,
                              hipStream_t stream) {
    const int*   wid = (const int*)d_in[0];      // (256, 2048) int32
    const float* emb = (const float*)d_in[1];    // (100000, 128) fp32
    const float* W   = (const float*)d_in[2];    // (128, 256) fp32
    const float* b   = (const float*)d_in[3];    // (128,) fp32
    float* out = (float*)d_out;                  // (256, 128) fp32

    __bf16* wpack = (__bf16*)d_ws;               // 64 frags * 64 * 8 = 64 KB
    __bf16* y     = wpack + 32768;               // (256,128,128) bf16 = 8 MB

    pack_w_kernel<<<64, 64, 0, stream>>>(W, wpack);
    tree128_kernel<<<4096, 256, 0, stream>>>(wid, emb, wpack, b, y);
    finish_kernel<<<256, 256, 0, stream>>>(y, wpack, b, out);
}

// Round 8
// 145.986 us; speedup vs baseline: 1.0210x; 1.0210x over previous
//
#include <hip/hip_runtime.h>

// RecursiveNN: 11-level binary tree, shared linear map W(128x256)+b, bf16 MFMA.
// pack_w: W -> per-lane MFMA B-fragment order (bf16).
// tree128: one block = 128 contiguous leaves; fp32 gather + packed cvt into a
//   144-row PADDED-stride LDS arena (STRIDE=136, 39,168 B -> 3 blocks/CU).
//   In-place level schedule, disjoint read/write row sets, 10 MFMA tiles,
//   8 barriers, levels 128->2. 4-way N-split (wave owns 32 cols, wf[16]=64
//   VGPR). Padded stride beats XOR swizzle (R7: swizzle VALU cost +18 us);
//   both measure 0 bank conflicts.
// tree32: one block = one batch; final 5 levels (32->1); fp32 output.

typedef __bf16 bf16x8 __attribute__((ext_vector_type(8)));
typedef __bf16 bf16x4 __attribute__((ext_vector_type(4)));
typedef float f32x4 __attribute__((ext_vector_type(4)));

#define STRIDE 136   // 128 cols + 8 pad bf16 = 272 B rows; 0 conflicts measured
#define NROWS 144    // 128-row working set + 16 transient rows = 39,168 B

// Pack W (fp32 128x256) into MFMA B-fragment lane order (bf16):
//   frag gf = nt*8 + kk (N-tile nt = output cols nt*16..+15), lane l:
//   elem j = W[o][d+j], o = nt*16 + (l&15), d = kk*32 + (l>>4)*8.
__global__ void pack_w_kernel(const float* __restrict__ W,
                              __bf16* __restrict__ wpack) {
    const int gf = blockIdx.x;       // 0..63
    const int l = threadIdx.x;       // 0..63
    const int nt = gf >> 3, kk = gf & 7;
    const int o = nt * 16 + (l & 15);
    const int d = kk * 32 + ((l >> 4) << 3);
    const float* src = W + o * 256 + d;
    bf16x8 h;
#pragma unroll
    for (int j = 0; j < 8; ++j) h[j] = (__bf16)src[j];
    *(bf16x8*)(wpack + (size_t)(gf * 64 + l) * 8) = h;
}

// One 16-row M-tile, 4-way N-split (this wave's 32 cols). Input node j
// (j = 2*me + k-half) at physical row: MODE 0: off+j; MODE 1 (post-L1
// piecewise): j<16 ? 128+j : j-16. Writes NOUT rows at dstb.. No barrier.
template <int NOUT, int MODE>
__device__ __forceinline__ void step(
    __bf16* __restrict__ L, int off, int dstb,
    const bf16x8* wf, const float* bval, int wv, int q, int lm)
{
    const int me = (NOUT >= 16) ? lm : (lm < NOUT ? lm : 0);  // clamp->bcast
    f32x4 acc[2];
    acc[0] = (f32x4){ bval[0], bval[0], bval[0], bval[0] };
    acc[1] = (f32x4){ bval[1], bval[1], bval[1], bval[1] };
#pragma unroll
    for (int kk = 0; kk < 8; ++kk) {
        const int j = 2 * me + (kk >> 2);
        const int row = MODE ? (j < 16 ? 128 + j : j - 16) : off + j;
        const int col = (kk & 3) * 32 + q * 8;
        const bf16x8 af = *(const bf16x8*)&L[row * STRIDE + col];
        acc[0] = __builtin_amdgcn_mfma_f32_16x16x32_bf16(af, wf[kk],     acc[0], 0, 0, 0);
        acc[1] = __builtin_amdgcn_mfma_f32_16x16x32_bf16(af, wf[8 + kk], acc[1], 0, 0, 0);
    }
#pragma unroll
    for (int nl = 0; nl < 2; ++nl) {
        const int col = (2 * wv + nl) * 16 + lm;       // D col = lane&15
        const bf16x4 hv = __builtin_convertvector(acc[nl], bf16x4);
#pragma unroll
        for (int r = 0; r < 4; ++r) {
            const int row = q * 4 + r;                 // D row = quad*4+reg
            if (NOUT >= 16 || row < NOUT)
                L[(dstb + row) * STRIDE + col] = hv[r];
        }
    }
}

// Final: 4 src rows (off..off+3) -> 2 roots straight to global (bf16).
__device__ __forceinline__ void final_tile(
    const __bf16* __restrict__ L, int off, __bf16* __restrict__ yrow,
    const bf16x8* wf, const float* bval, int wv, int q, int lm)
{
    const int me = (lm < 2) ? lm : 0;
    f32x4 acc[2];
    acc[0] = (f32x4){ bval[0], bval[0], bval[0], bval[0] };
    acc[1] = (f32x4){ bval[1], bval[1], bval[1], bval[1] };
#pragma unroll
    for (int kk = 0; kk < 8; ++kk) {
        const int row = off + 2 * me + (kk >> 2);
        const int col = (kk & 3) * 32 + q * 8;
        const bf16x8 af = *(const bf16x8*)&L[row * STRIDE + col];
        acc[0] = __builtin_amdgcn_mfma_f32_16x16x32_bf16(af, wf[kk],     acc[0], 0, 0, 0);
        acc[1] = __builtin_amdgcn_mfma_f32_16x16x32_bf16(af, wf[8 + kk], acc[1], 0, 0, 0);
    }
#pragma unroll
    for (int nl = 0; nl < 2; ++nl) {
        const int col = (2 * wv + nl) * 16 + lm;
        if (q == 0) {                                  // rows 0,1 = q0 regs 0,1
            yrow[0 * 128 + col] = (__bf16)acc[nl][0];
            yrow[1 * 128 + col] = (__bf16)acc[nl][1];
        }
    }
}

// Kernel 1: one block = 128 contiguous leaves of one batch; levels 128 -> 2.
// Row schedule (disjoint read/write sets per barrier interval):
//   gather -> rows 0..127                                   | B
//   L1 T0: rows  0-31  -> 128-143                           | B
//   L1 T1: rows 32-63  -> 0-15                              | B
//   L1 T2: rows 64-95  -> 16-31 ; T3: rows 96-127 -> 32-47  | B
//     (node n of level 1: n<16 ? row 128+n : row n-16)
//   L2 T0: n0-31 (piecewise) -> 48-63 ; T1: rows 16-47 -> 64-79 | B
//   L3: rows 48-79 -> 0-15                                  | B
//   L4: rows 0-15 -> 16-23                                  | B
//   L5: rows 16-23 -> 0-3                                   | B
//   L6: rows 0-3 -> 2 roots to global y (bf16)
__global__ __launch_bounds__(256) void tree128_kernel(
    const int* __restrict__ wid, const float* __restrict__ emb,
    const __bf16* __restrict__ wpack, const float* __restrict__ bias,
    __bf16* __restrict__ yout)
{
    __shared__ __align__(16) __bf16 L[NROWS * STRIDE];  // 39,168 B
    const int tid = threadIdx.x;
    const int batch = blockIdx.x >> 4;   // 16 groups of 128 leaves per batch
    const int grp = blockIdx.x & 15;
    const int wv = tid >> 6, ln = tid & 63, q = ln >> 4, lm = ln & 15;

    // Gather 128 rows x 128 fp32 -> bf16 LDS (512B coalesced runs, packed cvt).
    {
        const int* wb = wid + batch * 2048 + grp * 128;
        int idreg[16];
#pragma unroll
        for (int i = 0; i < 16; ++i) idreg[i] = wb[(tid >> 5) + 8 * i];
#pragma unroll
        for (int i = 0; i < 16; ++i) {
            const int row = (tid >> 5) + 8 * i;
            const int c4 = tid & 31;
            const f32x4 v =
                *(const f32x4*)(emb + (size_t)idreg[i] * 128 + c4 * 4);
            *(bf16x4*)&L[row * STRIDE + c4 * 4] =
                __builtin_convertvector(v, bf16x4);
        }
    }

    // W fragments for this wave's 32 cols (N-tiles 2wv, 2wv+1): 64 VGPRs.
    bf16x8 wf[16];
    const bf16x8* wp = (const bf16x8*)wpack;
#pragma unroll
    for (int f = 0; f < 16; ++f) wf[f] = wp[(16 * wv + f) * 64 + ln];
    float bval[2];
    bval[0] = bias[(2 * wv + 0) * 16 + lm];
    bval[1] = bias[(2 * wv + 1) * 16 + lm];

    __syncthreads();
    step<16, 0>(L, 0, 128, wf, bval, wv, q, lm);   // L1 T0
    __syncthreads();
    step<16, 0>(L, 32, 0, wf, bval, wv, q, lm);    // L1 T1
    __syncthreads();
    step<16, 0>(L, 64, 16, wf, bval, wv, q, lm);   // L1 T2
    step<16, 0>(L, 96, 32, wf, bval, wv, q, lm);   // L1 T3
    __syncthreads();
    step<16, 1>(L, 0, 48, wf, bval, wv, q, lm);    // L2 T0 (piecewise reads)
    step<16, 0>(L, 16, 64, wf, bval, wv, q, lm);   // L2 T1
    __syncthreads();
    step<16, 0>(L, 48, 0, wf, bval, wv, q, lm);    // L3 (32 -> 16)
    __syncthreads();
    step<8, 0>(L, 0, 16, wf, bval, wv, q, lm);     // L4 (16 -> 8)
    __syncthreads();
    step<4, 0>(L, 16, 0, wf, bval, wv, q, lm);     // L5 (8 -> 4)
    __syncthreads();
    final_tile(L, 0, yout + (size_t)(batch * 32 + grp * 2) * 128,
               wf, bval, wv, q, lm);               // L6 (4 -> 2) -> global
}

// Kernel 2: one block = one batch; 32 subtree roots -> 5 levels -> fp32 row.
__global__ __launch_bounds__(256) void tree32_kernel(
    const __bf16* __restrict__ yin, const __bf16* __restrict__ wpack,
    const float* __restrict__ bias, float* __restrict__ out)
{
    __shared__ __align__(16) __bf16 buf[2][32 * STRIDE];  // ~17.4 KB
    const int tid = threadIdx.x;
    const int batch = blockIdx.x;
    const int wv = tid >> 6, ln = tid & 63, q = ln >> 4, lm = ln & 15;

    bf16x8 wf[16];
    const bf16x8* wp = (const bf16x8*)wpack;
#pragma unroll
    for (int f = 0; f < 16; ++f) wf[f] = wp[(16 * wv + f) * 64 + ln];
    float bval[2];
    bval[0] = bias[(2 * wv + 0) * 16 + lm];
    bval[1] = bias[(2 * wv + 1) * 16 + lm];

#pragma unroll
    for (int i = 0; i < 2; ++i) {
        const int flat = tid + 256 * i;
        const int row = flat >> 4;
        const int c8 = flat & 15;
        const bf16x8 v =
            *(const bf16x8*)(yin + (size_t)(batch * 32 + row) * 128 + c8 * 8);
        *(bf16x8*)&buf[0][row * STRIDE + c8 * 8] = v;
    }
    __syncthreads();

    int nin = 32, rb = 0;
    while (nin > 1) {
        const int nout = nin >> 1;
        const int me = (lm < nout) ? lm : 0;
        bf16x8 af[8];
#pragma unroll
        for (int kk = 0; kk < 8; ++kk) {
            const int hi = kk >> 2;
            const int col = (kk & 3) * 32 + q * 8;
            af[kk] = *(const bf16x8*)&buf[rb][(2 * me + hi) * STRIDE + col];
        }
#pragma unroll
        for (int nl = 0; nl < 2; ++nl) {
            f32x4 acc = { bval[nl], bval[nl], bval[nl], bval[nl] };
#pragma unroll
            for (int kk = 0; kk < 8; ++kk)
                acc = __builtin_amdgcn_mfma_f32_16x16x32_bf16(
                    af[kk], wf[nl * 8 + kk], acc, 0, 0, 0);
            const int col = (2 * wv + nl) * 16 + lm;
            if (nout == 1) {
                if (q == 0) out[(size_t)batch * 128 + col] = acc[0];
            } else {
                const bf16x4 hv = __builtin_convertvector(acc, bf16x4);
#pragma unroll
                for (int r = 0; r < 4; ++r) {
                    const int row = q * 4 + r;
                    if (row < nout)
                        buf[rb ^ 1][row * STRIDE + col] = hv[r];
                }
            }
        }
        __syncthreads();
        rb ^= 1;
        nin = nout;
    }
}

extern "C" void kernel_launch(void* const* d_in, const int* in_sizes, int n_in,
                              void* d_out, int out_size, void* d_ws, size_t ws_size,
                              hipStream_t stream) {
    const int*   wid = (const int*)d_in[0];      // (256, 2048) int32
    const float* emb = (const float*)d_in[1];    // (100000, 128) fp32
    const float* W   = (const float*)d_in[2];    // (128, 256) fp32
    const float* b   = (const float*)d_in[3];    // (128,) fp32
    float* out = (float*)d_out;                  // (256, 128) fp32

    __bf16* wpack = (__bf16*)d_ws;               // 64 frags * 64 * 8 = 64 KB
    __bf16* y     = wpack + 32768;               // (256,32,128) bf16 = 2 MB

    pack_w_kernel<<<64, 64, 0, stream>>>(W, wpack);
    tree128_kernel<<<4096, 256, 0, stream>>>(wid, emb, wpack, b, y);
    tree32_kernel<<<256, 256, 0, stream>>>(y, wpack, b, out);
}

// Round 9
// 140.554 us; speedup vs baseline: 1.0605x; 1.0387x over previous
//
#include <hip/hip_runtime.h>

// RecursiveNN: 11-level binary tree, shared linear map W(128x256)+b, bf16 MFMA.
// pack_w: W -> per-lane MFMA B-fragment order (bf16).
// tree128: one block = 128 contiguous leaves; fp32 gather + packed cvt into a
//   144-row PADDED-stride LDS arena (STRIDE=136, 39,424 B -> 3 blocks/CU).
//   In-place level schedule, disjoint read/write row sets, 10 MFMA tiles,
//   8 barriers, levels 128->2. 4-way N-split (wave owns 32 cols, wf[16]=64
//   VGPR). CRITICAL: A-fragments are BATCH-loaded into af[8] before the MFMA
//   loop — R7/R8's interleaved load-use serialized ds_read latency against
//   the accumulator chain (VGPR 52, both pipes <25% busy, 68 us vs R4's 49).
// tree32: one block = one batch; final 5 levels (32->1); fp32 output.

typedef __bf16 bf16x8 __attribute__((ext_vector_type(8)));
typedef __bf16 bf16x4 __attribute__((ext_vector_type(4)));
typedef float f32x4 __attribute__((ext_vector_type(4)));

#define STRIDE 136   // 128 cols + 8 pad bf16 = 272 B rows; 0 conflicts measured
#define NROWS 144    // 128-row working set + 16 transient rows = 39,168 B

// Pack W (fp32 128x256) into MFMA B-fragment lane order (bf16):
//   frag gf = nt*8 + kk (N-tile nt = output cols nt*16..+15), lane l:
//   elem j = W[o][d+j], o = nt*16 + (l&15), d = kk*32 + (l>>4)*8.
__global__ void pack_w_kernel(const float* __restrict__ W,
                              __bf16* __restrict__ wpack) {
    const int gf = blockIdx.x;       // 0..63
    const int l = threadIdx.x;       // 0..63
    const int nt = gf >> 3, kk = gf & 7;
    const int o = nt * 16 + (l & 15);
    const int d = kk * 32 + ((l >> 4) << 3);
    const float* src = W + o * 256 + d;
    bf16x8 h;
#pragma unroll
    for (int j = 0; j < 8; ++j) h[j] = (__bf16)src[j];
    *(bf16x8*)(wpack + (size_t)(gf * 64 + l) * 8) = h;
}

// One 16-row M-tile, 4-way N-split (this wave's 32 cols). Input node j
// (j = 2*me + k-half) at physical row: MODE 0: off+j; MODE 1 (post-L1
// piecewise): j<16 ? 128+j : j-16. Writes NOUT rows at dstb.. No barrier.
// af[8] batch-loaded FIRST (8 ds_read_b128 in flight), then 16 MFMAs.
template <int NOUT, int MODE>
__device__ __forceinline__ void step(
    __bf16* __restrict__ L, int off, int dstb,
    const bf16x8* wf, const float* bval, int wv, int q, int lm)
{
    const int me = (NOUT >= 16) ? lm : (lm < NOUT ? lm : 0);  // clamp->bcast
    bf16x8 af[8];
#pragma unroll
    for (int kk = 0; kk < 8; ++kk) {
        const int j = 2 * me + (kk >> 2);
        const int row = MODE ? (j < 16 ? 128 + j : j - 16) : off + j;
        const int col = (kk & 3) * 32 + q * 8;
        af[kk] = *(const bf16x8*)&L[row * STRIDE + col];
    }
    f32x4 acc[2];
    acc[0] = (f32x4){ bval[0], bval[0], bval[0], bval[0] };
    acc[1] = (f32x4){ bval[1], bval[1], bval[1], bval[1] };
#pragma unroll
    for (int kk = 0; kk < 8; ++kk) {
        acc[0] = __builtin_amdgcn_mfma_f32_16x16x32_bf16(af[kk], wf[kk],     acc[0], 0, 0, 0);
        acc[1] = __builtin_amdgcn_mfma_f32_16x16x32_bf16(af[kk], wf[8 + kk], acc[1], 0, 0, 0);
    }
#pragma unroll
    for (int nl = 0; nl < 2; ++nl) {
        const int col = (2 * wv + nl) * 16 + lm;       // D col = lane&15
        const bf16x4 hv = __builtin_convertvector(acc[nl], bf16x4);
#pragma unroll
        for (int r = 0; r < 4; ++r) {
            const int row = q * 4 + r;                 // D row = quad*4+reg
            if (NOUT >= 16 || row < NOUT)
                L[(dstb + row) * STRIDE + col] = hv[r];
        }
    }
}

// Final: 4 src rows (off..off+3) -> 2 roots straight to global (bf16).
__device__ __forceinline__ void final_tile(
    const __bf16* __restrict__ L, int off, __bf16* __restrict__ yrow,
    const bf16x8* wf, const float* bval, int wv, int q, int lm)
{
    const int me = (lm < 2) ? lm : 0;
    bf16x8 af[8];
#pragma unroll
    for (int kk = 0; kk < 8; ++kk) {
        const int row = off + 2 * me + (kk >> 2);
        const int col = (kk & 3) * 32 + q * 8;
        af[kk] = *(const bf16x8*)&L[row * STRIDE + col];
    }
    f32x4 acc[2];
    acc[0] = (f32x4){ bval[0], bval[0], bval[0], bval[0] };
    acc[1] = (f32x4){ bval[1], bval[1], bval[1], bval[1] };
#pragma unroll
    for (int kk = 0; kk < 8; ++kk) {
        acc[0] = __builtin_amdgcn_mfma_f32_16x16x32_bf16(af[kk], wf[kk],     acc[0], 0, 0, 0);
        acc[1] = __builtin_amdgcn_mfma_f32_16x16x32_bf16(af[kk], wf[8 + kk], acc[1], 0, 0, 0);
    }
#pragma unroll
    for (int nl = 0; nl < 2; ++nl) {
        const int col = (2 * wv + nl) * 16 + lm;
        if (q == 0) {                                  // rows 0,1 = q0 regs 0,1
            yrow[0 * 128 + col] = (__bf16)acc[nl][0];
            yrow[1 * 128 + col] = (__bf16)acc[nl][1];
        }
    }
}

// Kernel 1: one block = 128 contiguous leaves of one batch; levels 128 -> 2.
// Row schedule (disjoint read/write sets per barrier interval):
//   gather -> rows 0..127                                   | B
//   L1 T0: rows  0-31  -> 128-143                           | B
//   L1 T1: rows 32-63  -> 0-15                              | B
//   L1 T2: rows 64-95  -> 16-31 ; T3: rows 96-127 -> 32-47  | B
//     (node n of level 1: n<16 ? row 128+n : row n-16)
//   L2 T0: n0-31 (piecewise) -> 48-63 ; T1: rows 16-47 -> 64-79 | B
//   L3: rows 48-79 -> 0-15                                  | B
//   L4: rows 0-15 -> 16-23                                  | B
//   L5: rows 16-23 -> 0-3                                   | B
//   L6: rows 0-3 -> 2 roots to global y (bf16)
__global__ __launch_bounds__(256) void tree128_kernel(
    const int* __restrict__ wid, const float* __restrict__ emb,
    const __bf16* __restrict__ wpack, const float* __restrict__ bias,
    __bf16* __restrict__ yout)
{
    __shared__ __align__(16) __bf16 L[NROWS * STRIDE];  // 39,168 B
    const int tid = threadIdx.x;
    const int batch = blockIdx.x >> 4;   // 16 groups of 128 leaves per batch
    const int grp = blockIdx.x & 15;
    const int wv = tid >> 6, ln = tid & 63, q = ln >> 4, lm = ln & 15;

    // Gather 128 rows x 128 fp32 -> bf16 LDS (512B coalesced runs, packed cvt).
    {
        const int* wb = wid + batch * 2048 + grp * 128;
        int idreg[16];
#pragma unroll
        for (int i = 0; i < 16; ++i) idreg[i] = wb[(tid >> 5) + 8 * i];
#pragma unroll
        for (int i = 0; i < 16; ++i) {
            const int row = (tid >> 5) + 8 * i;
            const int c4 = tid & 31;
            const f32x4 v =
                *(const f32x4*)(emb + (size_t)idreg[i] * 128 + c4 * 4);
            *(bf16x4*)&L[row * STRIDE + c4 * 4] =
                __builtin_convertvector(v, bf16x4);
        }
    }

    // W fragments for this wave's 32 cols (N-tiles 2wv, 2wv+1): 64 VGPRs.
    bf16x8 wf[16];
    const bf16x8* wp = (const bf16x8*)wpack;
#pragma unroll
    for (int f = 0; f < 16; ++f) wf[f] = wp[(16 * wv + f) * 64 + ln];
    float bval[2];
    bval[0] = bias[(2 * wv + 0) * 16 + lm];
    bval[1] = bias[(2 * wv + 1) * 16 + lm];

    __syncthreads();
    step<16, 0>(L, 0, 128, wf, bval, wv, q, lm);   // L1 T0
    __syncthreads();
    step<16, 0>(L, 32, 0, wf, bval, wv, q, lm);    // L1 T1
    __syncthreads();
    step<16, 0>(L, 64, 16, wf, bval, wv, q, lm);   // L1 T2
    step<16, 0>(L, 96, 32, wf, bval, wv, q, lm);   // L1 T3
    __syncthreads();
    step<16, 1>(L, 0, 48, wf, bval, wv, q, lm);    // L2 T0 (piecewise reads)
    step<16, 0>(L, 16, 64, wf, bval, wv, q, lm);   // L2 T1
    __syncthreads();
    step<16, 0>(L, 48, 0, wf, bval, wv, q, lm);    // L3 (32 -> 16)
    __syncthreads();
    step<8, 0>(L, 0, 16, wf, bval, wv, q, lm);     // L4 (16 -> 8)
    __syncthreads();
    step<4, 0>(L, 16, 0, wf, bval, wv, q, lm);     // L5 (8 -> 4)
    __syncthreads();
    final_tile(L, 0, yout + (size_t)(batch * 32 + grp * 2) * 128,
               wf, bval, wv, q, lm);               // L6 (4 -> 2) -> global
}

// Kernel 2: one block = one batch; 32 subtree roots -> 5 levels -> fp32 row.
__global__ __launch_bounds__(256) void tree32_kernel(
    const __bf16* __restrict__ yin, const __bf16* __restrict__ wpack,
    const float* __restrict__ bias, float* __restrict__ out)
{
    __shared__ __align__(16) __bf16 buf[2][32 * STRIDE];  // ~17.4 KB
    const int tid = threadIdx.x;
    const int batch = blockIdx.x;
    const int wv = tid >> 6, ln = tid & 63, q = ln >> 4, lm = ln & 15;

    bf16x8 wf[16];
    const bf16x8* wp = (const bf16x8*)wpack;
#pragma unroll
    for (int f = 0; f < 16; ++f) wf[f] = wp[(16 * wv + f) * 64 + ln];
    float bval[2];
    bval[0] = bias[(2 * wv + 0) * 16 + lm];
    bval[1] = bias[(2 * wv + 1) * 16 + lm];

#pragma unroll
    for (int i = 0; i < 2; ++i) {
        const int flat = tid + 256 * i;
        const int row = flat >> 4;
        const int c8 = flat & 15;
        const bf16x8 v =
            *(const bf16x8*)(yin + (size_t)(batch * 32 + row) * 128 + c8 * 8);
        *(bf16x8*)&buf[0][row * STRIDE + c8 * 8] = v;
    }
    __syncthreads();

    int nin = 32, rb = 0;
    while (nin > 1) {
        const int nout = nin >> 1;
        const int me = (lm < nout) ? lm : 0;
        bf16x8 af[8];
#pragma unroll
        for (int kk = 0; kk < 8; ++kk) {
            const int hi = kk >> 2;
            const int col = (kk & 3) * 32 + q * 8;
            af[kk] = *(const bf16x8*)&buf[rb][(2 * me + hi) * STRIDE + col];
        }
#pragma unroll
        for (int nl = 0; nl < 2; ++nl) {
            f32x4 acc = { bval[nl], bval[nl], bval[nl], bval[nl] };
#pragma unroll
            for (int kk = 0; kk < 8; ++kk)
                acc = __builtin_amdgcn_mfma_f32_16x16x32_bf16(
                    af[kk], wf[nl * 8 + kk], acc, 0, 0, 0);
            const int col = (2 * wv + nl) * 16 + lm;
            if (nout == 1) {
                if (q == 0) out[(size_t)batch * 128 + col] = acc[0];
            } else {
                const bf16x4 hv = __builtin_convertvector(acc, bf16x4);
#pragma unroll
                for (int r = 0; r < 4; ++r) {
                    const int row = q * 4 + r;
                    if (row < nout)
                        buf[rb ^ 1][row * STRIDE + col] = hv[r];
                }
            }
        }
        __syncthreads();
        rb ^= 1;
        nin = nout;
    }
}

extern "C" void kernel_launch(void* const* d_in, const int* in_sizes, int n_in,
                              void* d_out, int out_size, void* d_ws, size_t ws_size,
                              hipStream_t stream) {
    const int*   wid = (const int*)d_in[0];      // (256, 2048) int32
    const float* emb = (const float*)d_in[1];    // (100000, 128) fp32
    const float* W   = (const float*)d_in[2];    // (128, 256) fp32
    const float* b   = (const float*)d_in[3];    // (128,) fp32
    float* out = (float*)d_out;                  // (256, 128) fp32

    __bf16* wpack = (__bf16*)d_ws;               // 64 frags * 64 * 8 = 64 KB
    __bf16* y     = wpack + 32768;               // (256,32,128) bf16 = 2 MB

    pack_w_kernel<<<64, 64, 0, stream>>>(W, wpack);
    tree128_kernel<<<4096, 256, 0, stream>>>(wid, emb, wpack, b, y);
    tree32_kernel<<<256, 256, 0, stream>>>(y, wpack, b, out);
}